// Round 1
// 572.404 us; speedup vs baseline: 1.1623x; 1.1623x over previous
//
#include <hip/hip_runtime.h>
#include <cstdint>
#include <cstddef>

#define NB 512
#define N_PER 2048
#define NC 64
#define DEG 16
#define KSEL 1024
#define NTOT (NB * N_PER)        // 1048576 nodes
#define ETOT (NTOT * DEG)        // 16777216 edges
#define NOUT (NB * KSEL)         // 524288 kept nodes

#define T 512                    // threads per block (8 waves)
#define EPT 4                    // sort elements per thread (N_PER / T)

// d_out layout (float32; int values < 2^24 exact):
//   [0)          x_out      NOUT*NC  = 33554432
//   [33554432)   new_edge   2*ETOT   = 33554432
//   [67108864)   new_batch  NOUT
//   [67633152)   perm       NOUT
//   [68157440)   score      NOUT

// One block per graph. Phases:
//  1) f64 dot per node (tanh is monotone -> sort by raw dot; tanh only for kept)
//  2) bitonic sort of 2048 keys: registers (j<4) + shfl_xor (j=4..128) +
//     6 conflict-free LDS stages (j=256,512,1024). ~14 barriers vs 66.
//  3) outputs + LDS node map
//  4) gather x_out (per-graph local)
//  5) edge remap through LDS lmap (per-graph local)
__global__ __launch_bounds__(T) void fused_topk_kernel(
    const float* __restrict__ x, const float* __restrict__ p,
    const int* __restrict__ ei,
    float* __restrict__ out_x, float* __restrict__ out_edge,
    float* __restrict__ out_batch, float* __restrict__ out_perm,
    float* __restrict__ out_score) {
  __shared__ unsigned long long key2[EPT][T];  // 16 KB, slot-major (conflict-free)
  __shared__ int lmap[N_PER];                  // 8 KB: local idx -> new global id or -1
  __shared__ int klist[KSEL];                  // 4 KB: kept position -> local idx
  __shared__ float kscore[KSEL];               // 4 KB
  __shared__ double p_s[NC];
  __shared__ double norm_s;

  const int tid = threadIdx.x;
  const int b = blockIdx.x;
  const int base = b * N_PER;

  if (tid < NC) p_s[tid] = (double)p[tid];
  __syncthreads();
  if (tid == 0) {
    double s = 0.0;
    for (int i = 0; i < NC; ++i) s += p_s[i] * p_s[i];
    norm_s = sqrt(s);
  }

  // ---- Phase 1: f64 dot -> packed sort key, written slot-major into key2 ----
  // 16 lanes per row (float4 each = 64 channels); 32 rows per pass.
  const int lane = tid & 15;
  const int rowg = tid >> 4;  // 0..31
  const double pw0 = p_s[lane * 4 + 0];
  const double pw1 = p_s[lane * 4 + 1];
  const double pw2 = p_s[lane * 4 + 2];
  const double pw3 = p_s[lane * 4 + 3];
  const float4* xrow = (const float4*)(x + (size_t)base * NC);

  for (int r0 = 0; r0 < N_PER; r0 += 32) {
    const int row = r0 + rowg;
    float4 v = xrow[row * 16 + lane];
    double part = (double)v.x * pw0 + (double)v.y * pw1 +
                  (double)v.z * pw2 + (double)v.w * pw3;
    part += __shfl_xor(part, 8, 16);
    part += __shfl_xor(part, 4, 16);
    part += __shfl_xor(part, 2, 16);
    part += __shfl_xor(part, 1, 16);
    if (lane == 0) {
      // ascending-sort order == descending dot, tie -> lower idx.
      unsigned long long u = (unsigned long long)__double_as_longlong(part);
      unsigned long long asc =
          (u & 0x8000000000000000ULL) ? ~u : (u | 0x8000000000000000ULL);
      unsigned long long desc = ~asc;
      key2[row & 3][row >> 2] = (desc & ~2047ULL) | (unsigned long long)row;
    }
  }
  __syncthreads();

  // ---- Phase 2: bitonic sort, 4 keys/thread in registers ----
  unsigned long long r[EPT];
#pragma unroll
  for (int s = 0; s < EPT; ++s) r[s] = key2[s][tid];

  auto CE = [](unsigned long long& a, unsigned long long& c, bool up) {
    if ((a > c) == up) { unsigned long long t = a; a = c; c = t; }
  };
  auto shfl_stage = [&](int m, bool up) {
    const bool keepmin = (((tid & m) == 0) == up);
#pragma unroll
    for (int s = 0; s < EPT; ++s) {
      unsigned long long o = __shfl_xor(r[s], m, 64);
      const bool take = keepmin ? (o < r[s]) : (o > r[s]);
      if (take) r[s] = o;
    }
  };
  auto lds_stage = [&](int m, bool up) {
    __syncthreads();
#pragma unroll
    for (int s = 0; s < EPT; ++s) key2[s][tid] = r[s];
    __syncthreads();
    const bool keepmin = (((tid & m) == 0) == up);
#pragma unroll
    for (int s = 0; s < EPT; ++s) {
      unsigned long long o = key2[s][tid ^ m];
      const bool take = keepmin ? (o < r[s]) : (o > r[s]);
      if (take) r[s] = o;
    }
  };

  // k = 2: e&2 = s&2
  CE(r[0], r[1], true);
  CE(r[2], r[3], false);
  // k = 4: e&4 = (tid&1)<<2
  {
    const bool up = ((tid & 1) == 0);
    CE(r[0], r[2], up); CE(r[1], r[3], up);
    CE(r[0], r[1], up); CE(r[2], r[3], up);
  }
  // k = 8 .. 2048: e&k = (tid & (k>>2)) << 2
#pragma unroll
  for (int k = 8; k <= N_PER; k <<= 1) {
    const bool up = ((tid & (k >> 2)) == 0);
#pragma unroll
    for (int j = (k >> 1); j >= 256; j >>= 1) lds_stage(j >> 2, up);  // cross-wave
#pragma unroll
    for (int j = ((k >> 1) > 128 ? 128 : (k >> 1)); j >= 4; j >>= 1)
      shfl_stage(j >> 2, up);                                          // intra-wave
    CE(r[0], r[2], up); CE(r[1], r[3], up);                            // j = 2
    CE(r[0], r[1], up); CE(r[2], r[3], up);                            // j = 1
  }

  // ---- Phase 3: outputs + LDS node map ----
  __syncthreads();  // key2 reads done (sort finished); lmap/klist are separate
  const double norm = norm_s;
#pragma unroll
  for (int s = 0; s < EPT; ++s) {
    const int pos = tid * EPT + s;
    const int idx = (int)(r[s] & 2047ULL);
    if (pos < KSEL) {
      // recover dot from key (low 11 mantissa bits lost: rel err ~2^-41)
      unsigned long long desc = r[s] & ~2047ULL;
      unsigned long long asc = ~desc;
      unsigned long long u = (asc & 0x8000000000000000ULL)
                                 ? (asc ^ 0x8000000000000000ULL)
                                 : ~asc;
      const double dot = __longlong_as_double((long long)u);
      const float sc = tanhf((float)(dot / norm));
      const int nid = b * KSEL + pos;
      out_batch[nid] = (float)b;
      out_perm[nid] = (float)(base + idx);
      out_score[nid] = sc;
      klist[pos] = idx;
      kscore[pos] = sc;
      lmap[idx] = nid;
    } else {
      lmap[idx] = -1;
    }
  }
  __syncthreads();

  // ---- Phase 4: gather x_out = x[perm] * score (32 rows / iter) ----
  const float4* xg = (const float4*)x;
  float4* xo = (float4*)out_x;
#pragma unroll 4
  for (int rr = 0; rr < KSEL; rr += 32) {
    const int row = rr + rowg;
    const int idx = klist[row];
    const float sc = kscore[row];
    float4 v = xg[(size_t)(base + idx) * 16 + lane];
    v.x *= sc; v.y *= sc; v.z *= sc; v.w *= sc;
    xo[(size_t)(b * KSEL + row) * 16 + lane] = v;
  }

  // ---- Phase 5: edge remap through LDS lmap ----
  const int nE4 = N_PER * DEG / 4;  // 8192 int4 per row of edge_index
  const int4* s_ei = (const int4*)ei + (size_t)b * nE4;
  const int4* d_ei = (const int4*)(ei + (size_t)ETOT) + (size_t)b * nE4;
  float4* o_s = (float4*)out_edge + (size_t)b * nE4;
  float4* o_d = (float4*)(out_edge + (size_t)ETOT) + (size_t)b * nE4;
#pragma unroll 2
  for (int i = tid; i < nE4; i += T) {
    const int4 s4 = s_ei[i];
    const int4 d4 = d_ei[i];
    const int ns0 = lmap[s4.x - base], ns1 = lmap[s4.y - base];
    const int ns2 = lmap[s4.z - base], ns3 = lmap[s4.w - base];
    const int nd0 = lmap[d4.x - base], nd1 = lmap[d4.y - base];
    const int nd2 = lmap[d4.z - base], nd3 = lmap[d4.w - base];
    float4 os, od;
    const bool k0 = (ns0 >= 0) && (nd0 >= 0);
    const bool k1 = (ns1 >= 0) && (nd1 >= 0);
    const bool k2 = (ns2 >= 0) && (nd2 >= 0);
    const bool k3 = (ns3 >= 0) && (nd3 >= 0);
    os.x = k0 ? (float)ns0 : -1.0f; od.x = k0 ? (float)nd0 : -1.0f;
    os.y = k1 ? (float)ns1 : -1.0f; od.y = k1 ? (float)nd1 : -1.0f;
    os.z = k2 ? (float)ns2 : -1.0f; od.z = k2 ? (float)nd2 : -1.0f;
    os.w = k3 ? (float)ns3 : -1.0f; od.w = k3 ? (float)nd3 : -1.0f;
    o_s[i] = os;
    o_d[i] = od;
  }
}

extern "C" void kernel_launch(void* const* d_in, const int* in_sizes, int n_in,
                              void* d_out, int out_size, void* d_ws,
                              size_t ws_size, hipStream_t stream) {
  const float* x = (const float*)d_in[0];
  const int* ei = (const int*)d_in[1];
  // d_in[2] = batch (implied by construction; unused)
  const float* p = (const float*)d_in[3];

  float* out = (float*)d_out;
  float* out_x = out;                // 33554432
  float* out_edge = out + 33554432;  // 33554432
  float* out_batch = out + 67108864;
  float* out_perm = out + 67633152;
  float* out_score = out + 68157440;

  fused_topk_kernel<<<NB, T, 0, stream>>>(x, p, ei, out_x, out_edge, out_batch,
                                          out_perm, out_score);
}